// Round 8
// baseline (208.269 us; speedup 1.0000x reference)
//
#include <hip/hip_runtime.h>
#include <hip/hip_bf16.h>

#define NN 50000
#define HH 128
#define NHEAD 4
#define HD 32
#define EE 800000
#define LN_EPS 1e-5f
#define ROWS_PAD 50048   // 782 * 64
#define SCAN_NB 98       // ceil(NN/512)

typedef __bf16 bf16x8 __attribute__((ext_vector_type(8)));
typedef short  s16x8  __attribute__((ext_vector_type(8)));
typedef float  f32x4  __attribute__((ext_vector_type(4)));

__device__ __forceinline__ f32x4 mfma_bf16(s16x8 a, s16x8 b, f32x4 c) {
    return __builtin_amdgcn_mfma_f32_16x16x32_bf16((bf16x8)a, (bf16x8)b, c, 0, 0, 0);
}

__device__ __forceinline__ unsigned short f2bf(float f) {
    union { float f; unsigned int u; } v; v.f = f;
    unsigned int u = v.u + 0x7FFFu + ((v.u >> 16) & 1u);  // RNE
    return (unsigned short)(u >> 16);
}
__device__ __forceinline__ float bf2f(unsigned short h) {
    union { unsigned int u; float f; } v; v.u = ((unsigned int)h) << 16;
    return v.f;
}
__device__ __forceinline__ float bflo(unsigned int w) { return __uint_as_float(w << 16); }
__device__ __forceinline__ float bfhi(unsigned int w) { return __uint_as_float(w & 0xffff0000u); }

// ---------------- index dtype probe ----------------
__global__ void detect_idx_kernel(const unsigned int* __restrict__ buf, int* __restrict__ flag) {
    if (blockIdx.x == 0 && threadIdx.x == 0) {
        int is64 = 1;
        for (int i = 0; i < 64; ++i) {
            if (buf[2 * i + 1] != 0u) { is64 = 0; break; }
        }
        *flag = is64;
    }
}

// histogram destination degrees + record each edge's rank within its segment
__global__ void hist_kernel(const void* __restrict__ ei, const int* __restrict__ flag,
                            int* __restrict__ deg, int* __restrict__ rank) {
    int i = (blockIdx.x * blockDim.x + threadIdx.x) * 2;
    if (i >= EE) return;
    int r0, r1;
    if (*flag) {
        longlong2 rv = *(const longlong2*)((const long long*)ei + i);
        r0 = (int)rv.x; r1 = (int)rv.y;
    } else {
        int2 rv = *(const int2*)((const int*)ei + i);
        r0 = rv.x; r1 = rv.y;
    }
    int ra = atomicAdd(&deg[r0], 1);
    int rb = atomicAdd(&deg[r1], 1);
    *(int2*)(rank + i) = make_int2(ra, rb);
}

// ---------------- scan of degrees ----------------
__global__ __launch_bounds__(512) void scan_a_kernel(const int* __restrict__ deg,
                                                     int* __restrict__ bsum) {
    __shared__ int red[8];
    const int t = threadIdx.x;
    const int gid = blockIdx.x * 512 + t;
    int v = (gid < NN) ? deg[gid] : 0;
    #pragma unroll
    for (int o = 1; o < 64; o <<= 1) v += __shfl_xor(v, o);
    if ((t & 63) == 0) red[t >> 6] = v;
    __syncthreads();
    if (t == 0) {
        int s = 0;
        #pragma unroll
        for (int k = 0; k < 8; ++k) s += red[k];
        bsum[blockIdx.x] = s;
    }
}

__global__ __launch_bounds__(512) void scan_c_kernel(const int* __restrict__ deg,
                                                     const int* __restrict__ bsum,
                                                     int* __restrict__ rstart) {
    __shared__ int wsum[8];
    __shared__ int blockoff;
    const int t = threadIdx.x;
    const int gid = blockIdx.x * 512 + t;
    const int lane = t & 63, w = t >> 6;
    if (t < 64) {
        int s = 0;
        for (int k = t; k < blockIdx.x; k += 64) s += bsum[k];
        #pragma unroll
        for (int o = 1; o < 64; o <<= 1) s += __shfl_xor(s, o);
        if (t == 0) blockoff = s;
    }
    int v = (gid < NN) ? deg[gid] : 0;
    int incl = v;
    #pragma unroll
    for (int o = 1; o < 64; o <<= 1) {
        int u = __shfl_up(incl, o);
        if (lane >= o) incl += u;
    }
    if (lane == 63) wsum[w] = incl;
    __syncthreads();
    int woff = 0;
    for (int k = 0; k < w; ++k) woff += wsum[k];
    int excl = blockoff + woff + incl - v;
    if (gid < NN) rstart[gid] = excl;
    if (gid == 0) rstart[NN] = EE;
}

// atomic-free scatter using precomputed ranks
__global__ void scatter_kernel(const void* __restrict__ ei, const int* __restrict__ flag,
                               const int* __restrict__ rank, const int* __restrict__ rstart,
                               int* __restrict__ colS) {
    int i = (blockIdx.x * blockDim.x + threadIdx.x) * 2;
    if (i >= EE) return;
    int r0, r1, c0, c1;
    if (*flag) {
        longlong2 rv = *(const longlong2*)((const long long*)ei + i);
        longlong2 cv = *(const longlong2*)((const long long*)ei + EE + i);
        r0 = (int)rv.x; r1 = (int)rv.y;
        c0 = (int)cv.x; c1 = (int)cv.y;
    } else {
        int2 rv = *(const int2*)((const int*)ei + i);
        int2 cv = *(const int2*)((const int*)ei + EE + i);
        r0 = rv.x; r1 = rv.y;
        c0 = cv.x; c1 = cv.y;
    }
    int2 rk = *(const int2*)(rank + i);
    colS[rstart[r0] + rk.x] = c0;
    colS[rstart[r1] + rk.y] = c1;
}

// ---------------- pack weights into MFMA b-fragment order ----------------
__global__ void pack_w_kernel(const float* __restrict__ Wq, const float* __restrict__ Wk,
                              const float* __restrict__ Wv, const float* __restrict__ W1,
                              const float* __restrict__ W2, unsigned short* __restrict__ wf) {
    int i = blockIdx.x * blockDim.x + threadIdx.x;
    if (i >= 98304) return;
    float val;
    if (i < 49152) {                      // QKV: ntiles=24, ksteps=4, K=128
        int j = i & 7, lane = (i >> 3) & 63, kk = (i >> 9) & 3, nt = i >> 11;
        int k = kk * 32 + (lane >> 4) * 8 + j;
        int n = nt * 16 + (lane & 15);    // 0..383
        const float* W = (n < 128) ? Wq : ((n < 256) ? Wk : Wv);
        val = W[k * HH + (n & 127)];
    } else if (i < 81920) {               // W1: ntiles=8, ksteps=8, K=256
        int local = i - 49152;
        int j = local & 7, lane = (local >> 3) & 63, kk = (local >> 9) & 7, nt = local >> 12;
        int k = kk * 32 + (lane >> 4) * 8 + j;
        int n = nt * 16 + (lane & 15);
        val = W1[k * HH + n];
    } else {                              // W2: ntiles=8, ksteps=4, K=128
        int local = i - 81920;
        int j = local & 7, lane = (local >> 3) & 63, kk = (local >> 9) & 3, nt = local >> 11;
        int k = kk * 32 + (lane >> 4) * 8 + j;
        int n = nt * 16 + (lane & 15);
        val = W2[k * HH + n];
    }
    wf[i] = f2bf(val);
}

// ---------------- fused x-pack + QKV GEMM via MFMA ----------------
__global__ __launch_bounds__(256) void qkvx_kernel(
        const float* __restrict__ x, const unsigned short* __restrict__ wf,
        const float* __restrict__ bq, const float* __restrict__ bk, const float* __restrict__ bv,
        unsigned short* __restrict__ xa,
        unsigned short* __restrict__ Qb, unsigned short* __restrict__ Kb,
        unsigned short* __restrict__ Vb) {
    const int wave = threadIdx.x >> 6, lane = threadIdx.x & 63;
    const int row0 = blockIdx.x * 64 + wave * 16;
    const int arow = row0 + (lane & 15);
    const int kbase = (lane >> 4) * 8;

    s16x8 a[4];
    if (arow < NN) {
        const float* xp = x + (size_t)arow * HH + kbase;
        #pragma unroll
        for (int kk = 0; kk < 4; ++kk) {
            float4 f0 = *(const float4*)(xp + kk * 32);
            float4 f1 = *(const float4*)(xp + kk * 32 + 4);
            s16x8 av;
            av[0] = (short)f2bf(f0.x); av[1] = (short)f2bf(f0.y);
            av[2] = (short)f2bf(f0.z); av[3] = (short)f2bf(f0.w);
            av[4] = (short)f2bf(f1.x); av[5] = (short)f2bf(f1.y);
            av[6] = (short)f2bf(f1.z); av[7] = (short)f2bf(f1.w);
            a[kk] = av;
            *(s16x8*)(xa + (size_t)arow * 256 + kbase + kk * 32) = av;
        }
    } else {
        #pragma unroll
        for (int kk = 0; kk < 4; ++kk) a[kk] = (s16x8)0;
    }

    f32x4 acc[24];
    #pragma unroll
    for (int nt = 0; nt < 24; ++nt) acc[nt] = (f32x4){0.f, 0.f, 0.f, 0.f};

    const s16x8* wfv = (const s16x8*)wf;
    #pragma unroll
    for (int nt = 0; nt < 24; ++nt) {
        #pragma unroll
        for (int kk = 0; kk < 4; ++kk) {
            s16x8 b = wfv[(nt * 4 + kk) * 64 + lane];
            acc[nt] = mfma_bf16(a[kk], b, acc[nt]);
        }
    }

    const int colb = lane & 15;
    const int rbase = row0 + (lane >> 4) * 4;
    #pragma unroll
    for (int nt = 0; nt < 24; ++nt) {
        const int mtx = nt >> 3;                  // 0:Q 1:K 2:V
        const int nc = (nt & 7) * 16 + colb;      // 0..127
        const float* bias_p = (mtx == 0) ? bq : ((mtx == 1) ? bk : bv);
        unsigned short* O = (mtx == 0) ? Qb : ((mtx == 1) ? Kb : Vb);
        float bias = bias_p[nc];
        #pragma unroll
        for (int r = 0; r < 4; ++r)
            O[(size_t)(rbase + r) * 128 + nc] = f2bf(acc[nt][r] + bias);
    }
}

// ---------------- attention helpers ----------------
__device__ __forceinline__ float dot32(uint4 k0, uint4 k1, uint4 k2, uint4 k3,
                                       const uint4 q[4]) {
    float dot = 0.f;
    uint4 kk[4] = {k0, k1, k2, k3};
    #pragma unroll
    for (int c = 0; c < 4; ++c) {
        unsigned int kw[4] = {kk[c].x, kk[c].y, kk[c].z, kk[c].w};
        unsigned int qw[4] = {q[c].x, q[c].y, q[c].z, q[c].w};
        #pragma unroll
        for (int d = 0; d < 4; ++d) {
            dot += bflo(qw[d]) * bflo(kw[d]);
            dot += bfhi(qw[d]) * bfhi(kw[d]);
        }
    }
    return dot;
}

__device__ __forceinline__ void smax_update(float s, int le, int cnt,
                                            float& m, float& l, float& p, float& fac) {
    float sm = s;
    sm = fmaxf(sm, __shfl_xor(sm, 4));
    sm = fmaxf(sm, __shfl_xor(sm, 8));
    sm = fmaxf(sm, __shfl_xor(sm, 16));
    sm = fmaxf(sm, __shfl_xor(sm, 32));
    const float mn = fmaxf(m, sm);
    p = (le < cnt) ? __expf(s - mn) : 0.f;
    float ps = p;
    ps += __shfl_xor(ps, 4);
    ps += __shfl_xor(ps, 8);
    ps += __shfl_xor(ps, 16);
    ps += __shfl_xor(ps, 32);
    fac = __expf(m - mn);  // first chunk: exp(-inf)=0
    l = l * fac + ps;
    m = mn;
}

__device__ __forceinline__ void pv_acc(const unsigned short* __restrict__ Vb,
                                       int col, float p, float fac,
                                       int half, int sl, int g2,
                                       float& a0, float& a1, float& a2, float& a3) {
    const float facbc = __shfl(fac, g2);
    a0 *= facbc; a1 *= facbc; a2 *= facbc; a3 *= facbc;
    #pragma unroll
    for (int e2 = 0; e2 < 8; ++e2) {
        const int e = 2 * e2 + half;
        const int   cbc = __shfl(col, 4 * e);
        const float pbc = __shfl(p, 4 * e + g2);
        const uint2 v2 = *(const uint2*)(Vb + (size_t)cbc * 128 + 4 * sl);
        a0 += pbc * bflo(v2.x);
        a1 += pbc * bfhi(v2.x);
        a2 += pbc * bflo(v2.y);
        a3 += pbc * bfhi(v2.y);
    }
}

// single-node chunk (tail path)
__device__ __forceinline__ void chunk_one(const unsigned short* __restrict__ Kb,
                                          const unsigned short* __restrict__ Vb,
                                          const int* __restrict__ colS,
                                          int e0, int c0, int deg, const uint4 q[4],
                                          int h, int le, int half, int sl, int g2,
                                          float& m, float& l,
                                          float& a0, float& a1, float& a2, float& a3) {
    const int cnt = min(16, deg - c0);
    int col = 0;
    if (le < cnt) col = colS[e0 + c0 + le];
    const uint4* kp = (const uint4*)(Kb + (size_t)col * 128 + h * 32);
    uint4 k0 = kp[0], k1 = kp[1], k2 = kp[2], k3 = kp[3];
    float s = -INFINITY;
    if (le < cnt) s = dot32(k0, k1, k2, k3, q) * 0.17677669529663689f;
    float p, fac;
    smax_update(s, le, cnt, m, l, p, fac);
    pv_acc(Vb, col, p, fac, half, sl, g2, a0, a1, a2, a3);
}

// ---------------- fused per-node attention: 2 nodes per wave, interleaved ----------------
// score phase: lane = local_edge*4 + head (lane-local 32-dim dot)
// PV phase: half = lane>>5 handles edges of that parity; lane owns dims 4*sl..4*sl+3
__global__ __launch_bounds__(256) void attn_kernel(
        const unsigned short* __restrict__ Qb, const unsigned short* __restrict__ Kb,
        const unsigned short* __restrict__ Vb, const int* __restrict__ rstart,
        const int* __restrict__ colS, unsigned short* __restrict__ xa) {
    const int wave = threadIdx.x >> 6;
    const int lane = threadIdx.x & 63;
    const int h = lane & 3;
    const int le = lane >> 2;
    const int half = lane >> 5;
    const int sl = lane & 31;
    const int g2 = sl >> 3;
    const int iA = (blockIdx.x * 4 + wave) * 2;   // grid = NN/8 blocks, NN even
    const int iB = iA + 1;

    // bounds: rstart[iA], rstart[iA+1], rstart[iA+2]
    const int e0A = rstart[iA];
    const int e1A = rstart[iA + 1];
    const int e1B = rstart[iA + 2];
    const int e0B = e1A;
    const int degA = e1A - e0A;
    const int degB = e1B - e0B;

    // Q for both nodes, packed bf16 (4 x uint4 each), this head's 32-dim slice
    uint4 qA[4], qB[4];
    {
        const uint4* qpA = (const uint4*)(Qb + (size_t)iA * 128 + h * 32);
        const uint4* qpB = (const uint4*)(Qb + (size_t)iB * 128 + h * 32);
        #pragma unroll
        for (int c = 0; c < 4; ++c) { qA[c] = qpA[c]; qB[c] = qpB[c]; }
    }

    float mA = -INFINITY, lA = 0.f, aA0 = 0.f, aA1 = 0.f, aA2 = 0.f, aA3 = 0.f;
    float mB = -INFINITY, lB = 0.f, aB0 = 0.f, aB1 = 0.f, aB2 = 0.f, aB3 = 0.f;

    int c0A = 0, c0B = 0;
    // lockstep: both nodes' chains in flight together
    while (c0A < degA && c0B < degB) {
        const int cntA = min(16, degA - c0A);
        const int cntB = min(16, degB - c0B);
        int colA = 0, colB = 0;
        if (le < cntA) colA = colS[e0A + c0A + le];
        if (le < cntB) colB = colS[e0B + c0B + le];
        const uint4* kpA = (const uint4*)(Kb + (size_t)colA * 128 + h * 32);
        const uint4* kpB = (const uint4*)(Kb + (size_t)colB * 128 + h * 32);
        // all 8 K loads issued before any dependent compute
        uint4 ka0 = kpA[0], ka1 = kpA[1], ka2 = kpA[2], ka3 = kpA[3];
        uint4 kb0 = kpB[0], kb1 = kpB[1], kb2 = kpB[2], kb3 = kpB[3];
        float sA = -INFINITY, sB = -INFINITY;
        if (le < cntA) sA = dot32(ka0, ka1, ka2, ka3, qA) * 0.17677669529663689f;
        if (le < cntB) sB = dot32(kb0, kb1, kb2, kb3, qB) * 0.17677669529663689f;
        float pA, facA, pB, facB;
        smax_update(sA, le, cntA, mA, lA, pA, facA);
        smax_update(sB, le, cntB, mB, lB, pB, facB);
        pv_acc(Vb, colA, pA, facA, half, sl, g2, aA0, aA1, aA2, aA3);
        pv_acc(Vb, colB, pB, facB, half, sl, g2, aB0, aB1, aB2, aB3);
        c0A += 16; c0B += 16;
    }
    // tails (rare: deg > 16 with unequal chunk counts)
    while (c0A < degA) {
        chunk_one(Kb, Vb, colS, e0A, c0A, degA, qA, h, le, half, sl, g2,
                  mA, lA, aA0, aA1, aA2, aA3);
        c0A += 16;
    }
    while (c0B < degB) {
        chunk_one(Kb, Vb, colS, e0B, c0B, degB, qB, h, le, half, sl, g2,
                  mB, lB, aB0, aB1, aB2, aB3);
        c0B += 16;
    }

    // combine edge-parity halves and write both nodes
    aA0 += __shfl_xor(aA0, 32); aA1 += __shfl_xor(aA1, 32);
    aA2 += __shfl_xor(aA2, 32); aA3 += __shfl_xor(aA3, 32);
    aB0 += __shfl_xor(aB0, 32); aB1 += __shfl_xor(aB1, 32);
    aB2 += __shfl_xor(aB2, 32); aB3 += __shfl_xor(aB3, 32);
    const float lfA = __shfl(lA, g2);
    const float lfB = __shfl(lB, g2);
    const float riA = (lfA > 0.f) ? 1.f / lfA : 0.f;
    const float riB = (lfB > 0.f) ? 1.f / lfB : 0.f;
    if (half == 0) {
        uint2 oA, oB;
        oA.x = ((unsigned int)f2bf(aA1 * riA) << 16) | (unsigned int)f2bf(aA0 * riA);
        oA.y = ((unsigned int)f2bf(aA3 * riA) << 16) | (unsigned int)f2bf(aA2 * riA);
        oB.x = ((unsigned int)f2bf(aB1 * riB) << 16) | (unsigned int)f2bf(aB0 * riB);
        oB.y = ((unsigned int)f2bf(aB3 * riB) << 16) | (unsigned int)f2bf(aB2 * riB);
        *(uint2*)(xa + (size_t)iA * 256 + 128 + 4 * sl) = oA;
        *(uint2*)(xa + (size_t)iB * 256 + 128 + 4 * sl) = oB;
    }
}

// ---------------- MLP1 via MFMA + ReLU + LayerNorm -> bf16 h ----------------
__global__ __launch_bounds__(256) void gemm_mlp1_kernel(
        const unsigned short* __restrict__ xa, const unsigned short* __restrict__ w1f,
        const float* __restrict__ b1, const float* __restrict__ ln_g,
        const float* __restrict__ ln_b, unsigned short* __restrict__ hb) {
    const int wave = threadIdx.x >> 6, lane = threadIdx.x & 63;
    const int row0 = blockIdx.x * 64 + wave * 16;
    const int arow = row0 + (lane & 15);

    s16x8 a[8];
    const unsigned short* ap = xa + (size_t)arow * 256 + (lane >> 4) * 8;
    #pragma unroll
    for (int kk = 0; kk < 8; ++kk) a[kk] = *(const s16x8*)(ap + kk * 32);

    f32x4 acc[8];
    #pragma unroll
    for (int nt = 0; nt < 8; ++nt) acc[nt] = (f32x4){0.f, 0.f, 0.f, 0.f};

    const s16x8* wfv = (const s16x8*)w1f;
    #pragma unroll
    for (int nt = 0; nt < 8; ++nt) {
        #pragma unroll
        for (int kk = 0; kk < 8; ++kk) {
            s16x8 b = wfv[(nt * 8 + kk) * 64 + lane];
            acc[nt] = mfma_bf16(a[kk], b, acc[nt]);
        }
    }

    const int colb = lane & 15;
    #pragma unroll
    for (int nt = 0; nt < 8; ++nt) {
        float bias = b1[nt * 16 + colb];
        #pragma unroll
        for (int r = 0; r < 4; ++r) {
            float v = acc[nt][r] + bias;
            acc[nt][r] = v > 0.f ? v : 0.f;
        }
    }
    float mu[4], rs[4];
    #pragma unroll
    for (int r = 0; r < 4; ++r) {
        float s = 0.f, q = 0.f;
        #pragma unroll
        for (int nt = 0; nt < 8; ++nt) { float v = acc[nt][r]; s += v; q += v * v; }
        #pragma unroll
        for (int msk = 1; msk < 16; msk <<= 1) {
            s += __shfl_xor(s, msk, 16);
            q += __shfl_xor(q, msk, 16);
        }
        float m_ = s * (1.f / 128.f);
        float var = q * (1.f / 128.f) - m_ * m_;
        mu[r] = m_;
        rs[r] = rsqrtf(var + LN_EPS);
    }
    const int rbase = row0 + (lane >> 4) * 4;
    #pragma unroll
    for (int nt = 0; nt < 8; ++nt) {
        int col = nt * 16 + colb;
        float g = ln_g[col], bb = ln_b[col];
        #pragma unroll
        for (int r = 0; r < 4; ++r) {
            float h = (acc[nt][r] - mu[r]) * rs[r] * g + bb;
            hb[(size_t)(rbase + r) * 128 + col] = f2bf(h);
        }
    }
}

// ---------------- MLP2 via MFMA + bias + residual (bf16 x from xa) -> f32 out ----------------
__global__ __launch_bounds__(256) void gemm_mlp2_kernel(
        const unsigned short* __restrict__ hb, const unsigned short* __restrict__ w2f,
        const float* __restrict__ b2, const unsigned short* __restrict__ xa,
        float* __restrict__ out) {
    const int wave = threadIdx.x >> 6, lane = threadIdx.x & 63;
    const int row0 = blockIdx.x * 64 + wave * 16;
    const int arow = row0 + (lane & 15);

    s16x8 a[4];
    const unsigned short* ap = hb + (size_t)arow * 128 + (lane >> 4) * 8;
    #pragma unroll
    for (int kk = 0; kk < 4; ++kk) a[kk] = *(const s16x8*)(ap + kk * 32);

    f32x4 acc[8];
    #pragma unroll
    for (int nt = 0; nt < 8; ++nt) acc[nt] = (f32x4){0.f, 0.f, 0.f, 0.f};

    const s16x8* wfv = (const s16x8*)w2f;
    #pragma unroll
    for (int nt = 0; nt < 8; ++nt) {
        #pragma unroll
        for (int kk = 0; kk < 4; ++kk) {
            s16x8 b = wfv[(nt * 4 + kk) * 64 + lane];
            acc[nt] = mfma_bf16(a[kk], b, acc[nt]);
        }
    }

    const int colb = lane & 15;
    const int rbase = row0 + (lane >> 4) * 4;
    #pragma unroll
    for (int nt = 0; nt < 8; ++nt) {
        int col = nt * 16 + colb;
        float bias = b2[col];
        #pragma unroll
        for (int r = 0; r < 4; ++r) {
            int row = rbase + r;
            if (row < NN)
                out[(size_t)row * 128 + col] =
                    acc[nt][r] + bias + bf2f(xa[(size_t)row * 256 + col]);
        }
    }
}

extern "C" void kernel_launch(void* const* d_in, const int* in_sizes, int n_in,
                              void* d_out, int out_size, void* d_ws, size_t ws_size,
                              hipStream_t stream) {
    const float* x    = (const float*)d_in[0];
    const void*  ei   = d_in[1];
    const float* Wq   = (const float*)d_in[2];
    const float* bq   = (const float*)d_in[3];
    const float* Wk   = (const float*)d_in[4];
    const float* bk   = (const float*)d_in[5];
    const float* Wv   = (const float*)d_in[6];
    const float* bv   = (const float*)d_in[7];
    const float* W1   = (const float*)d_in[8];
    const float* b1   = (const float*)d_in[9];
    const float* ln_g = (const float*)d_in[10];
    const float* ln_b = (const float*)d_in[11];
    const float* W2   = (const float*)d_in[12];
    const float* b2   = (const float*)d_in[13];
    float* out = (float*)d_out;

    char* ws = (char*)d_ws;
    size_t off = 0;
    auto alloc = [&](size_t bytes) {
        size_t o = off;
        off = (off + bytes + 255) & ~(size_t)255;
        return o;
    };
    size_t flag_o = alloc(sizeof(int));
    size_t deg_o  = alloc((size_t)NN * sizeof(int));
    size_t rank_o = alloc((size_t)EE * sizeof(int));
    size_t rs_o   = alloc((size_t)(NN + 1) * sizeof(int));
    size_t bsum_o = alloc((size_t)SCAN_NB * sizeof(int));
    size_t colS_o = alloc((size_t)EE * sizeof(int));
    size_t xa_o   = alloc((size_t)ROWS_PAD * 256 * sizeof(unsigned short));
    size_t wf_o   = alloc((size_t)98304 * sizeof(unsigned short));
    size_t Qb_o   = alloc((size_t)ROWS_PAD * 128 * sizeof(unsigned short));
    size_t Kb_o   = alloc((size_t)ROWS_PAD * 128 * sizeof(unsigned short));
    size_t Vb_o   = alloc((size_t)ROWS_PAD * 128 * sizeof(unsigned short));
    size_t hb_o   = Qb_o;  // h reuses Q (dead after attn)

    int* flag   = (int*)(ws + flag_o);
    int* deg    = (int*)(ws + deg_o);
    int* rank   = (int*)(ws + rank_o);
    int* rstart = (int*)(ws + rs_o);
    int* bsum   = (int*)(ws + bsum_o);
    int* colS   = (int*)(ws + colS_o);
    unsigned short* xa = (unsigned short*)(ws + xa_o);
    unsigned short* wf = (unsigned short*)(ws + wf_o);
    unsigned short* Qb = (unsigned short*)(ws + Qb_o);
    unsigned short* Kb = (unsigned short*)(ws + Kb_o);
    unsigned short* Vb = (unsigned short*)(ws + Vb_o);
    unsigned short* hb = (unsigned short*)(ws + hb_o);

    hipMemsetAsync(ws + deg_o, 0, (size_t)NN * sizeof(int), stream);

    detect_idx_kernel<<<1, 64, 0, stream>>>((const unsigned int*)ei, flag);
    hist_kernel<<<(EE / 2 + 255) / 256, 256, 0, stream>>>(ei, flag, deg, rank);
    scan_a_kernel<<<SCAN_NB, 512, 0, stream>>>(deg, bsum);
    scan_c_kernel<<<SCAN_NB, 512, 0, stream>>>(deg, bsum, rstart);
    scatter_kernel<<<(EE / 2 + 255) / 256, 256, 0, stream>>>(ei, flag, rank, rstart, colS);

    pack_w_kernel<<<98304 / 256, 256, 0, stream>>>(Wq, Wk, Wv, W1, W2, wf);

    qkvx_kernel<<<ROWS_PAD / 64, 256, 0, stream>>>(x, wf, bq, bk, bv, xa, Qb, Kb, Vb);

    attn_kernel<<<NN / 8, 256, 0, stream>>>(Qb, Kb, Vb, rstart, colS, xa);

    gemm_mlp1_kernel<<<ROWS_PAD / 64, 256, 0, stream>>>(xa, wf + 49152, b1, ln_g, ln_b, hb);

    gemm_mlp2_kernel<<<ROWS_PAD / 64, 256, 0, stream>>>(hb, wf + 81920, b2, xa, out);
}

// Round 9
// 190.406 us; speedup vs baseline: 1.0938x; 1.0938x over previous
//
#include <hip/hip_runtime.h>
#include <hip/hip_bf16.h>

#define NN 50000
#define HH 128
#define NHEAD 4
#define HD 32
#define EE 800000
#define LN_EPS 1e-5f
#define ROWS_PAD 50048   // 782 * 64
#define SCAN_NB 98       // ceil(NN/512)

typedef __bf16 bf16x8 __attribute__((ext_vector_type(8)));
typedef short  s16x8  __attribute__((ext_vector_type(8)));
typedef float  f32x4  __attribute__((ext_vector_type(4)));
typedef _Float16 h2   __attribute__((ext_vector_type(2)));

__device__ __forceinline__ f32x4 mfma_bf16(s16x8 a, s16x8 b, f32x4 c) {
    return __builtin_amdgcn_mfma_f32_16x16x32_bf16((bf16x8)a, (bf16x8)b, c, 0, 0, 0);
}

__device__ __forceinline__ unsigned short f2bf(float f) {
    union { float f; unsigned int u; } v; v.f = f;
    unsigned int u = v.u + 0x7FFFu + ((v.u >> 16) & 1u);  // RNE
    return (unsigned short)(u >> 16);
}
__device__ __forceinline__ float bf2f(unsigned short h) {
    union { unsigned int u; float f; } v; v.u = ((unsigned int)h) << 16;
    return v.f;
}
__device__ __forceinline__ float bflo(unsigned int w) { return __uint_as_float(w << 16); }
__device__ __forceinline__ float bfhi(unsigned int w) { return __uint_as_float(w & 0xffff0000u); }

__device__ __forceinline__ unsigned short f2h(float f) {
    _Float16 h = (_Float16)f;
    return __builtin_bit_cast(unsigned short, h);
}

#if defined(__has_builtin)
#if __has_builtin(__builtin_amdgcn_fdot2)
#define HAVE_FDOT2 1
#endif
#endif

// dot of two packed-f16 pairs accumulated into c
__device__ __forceinline__ float fdot2u(unsigned int a, unsigned int b, float c) {
#ifdef HAVE_FDOT2
    return __builtin_amdgcn_fdot2(__builtin_bit_cast(h2, a), __builtin_bit_cast(h2, b), c, false);
#else
    h2 ha = __builtin_bit_cast(h2, a), hb = __builtin_bit_cast(h2, b);
    return c + (float)ha[0] * (float)hb[0] + (float)ha[1] * (float)hb[1];
#endif
}

// ---------------- index dtype probe ----------------
__global__ void detect_idx_kernel(const unsigned int* __restrict__ buf, int* __restrict__ flag) {
    if (blockIdx.x == 0 && threadIdx.x == 0) {
        int is64 = 1;
        for (int i = 0; i < 64; ++i) {
            if (buf[2 * i + 1] != 0u) { is64 = 0; break; }
        }
        *flag = is64;
    }
}

// histogram destination degrees + record each edge's rank within its segment
__global__ void hist_kernel(const void* __restrict__ ei, const int* __restrict__ flag,
                            int* __restrict__ deg, int* __restrict__ rank) {
    int i = (blockIdx.x * blockDim.x + threadIdx.x) * 2;
    if (i >= EE) return;
    int r0, r1;
    if (*flag) {
        longlong2 rv = *(const longlong2*)((const long long*)ei + i);
        r0 = (int)rv.x; r1 = (int)rv.y;
    } else {
        int2 rv = *(const int2*)((const int*)ei + i);
        r0 = rv.x; r1 = rv.y;
    }
    int ra = atomicAdd(&deg[r0], 1);
    int rb = atomicAdd(&deg[r1], 1);
    *(int2*)(rank + i) = make_int2(ra, rb);
}

// ---------------- scan of degrees ----------------
__global__ __launch_bounds__(512) void scan_a_kernel(const int* __restrict__ deg,
                                                     int* __restrict__ bsum) {
    __shared__ int red[8];
    const int t = threadIdx.x;
    const int gid = blockIdx.x * 512 + t;
    int v = (gid < NN) ? deg[gid] : 0;
    #pragma unroll
    for (int o = 1; o < 64; o <<= 1) v += __shfl_xor(v, o);
    if ((t & 63) == 0) red[t >> 6] = v;
    __syncthreads();
    if (t == 0) {
        int s = 0;
        #pragma unroll
        for (int k = 0; k < 8; ++k) s += red[k];
        bsum[blockIdx.x] = s;
    }
}

__global__ __launch_bounds__(512) void scan_c_kernel(const int* __restrict__ deg,
                                                     const int* __restrict__ bsum,
                                                     int* __restrict__ rstart) {
    __shared__ int wsum[8];
    __shared__ int blockoff;
    const int t = threadIdx.x;
    const int gid = blockIdx.x * 512 + t;
    const int lane = t & 63, w = t >> 6;
    if (t < 64) {
        int s = 0;
        for (int k = t; k < blockIdx.x; k += 64) s += bsum[k];
        #pragma unroll
        for (int o = 1; o < 64; o <<= 1) s += __shfl_xor(s, o);
        if (t == 0) blockoff = s;
    }
    int v = (gid < NN) ? deg[gid] : 0;
    int incl = v;
    #pragma unroll
    for (int o = 1; o < 64; o <<= 1) {
        int u = __shfl_up(incl, o);
        if (lane >= o) incl += u;
    }
    if (lane == 63) wsum[w] = incl;
    __syncthreads();
    int woff = 0;
    for (int k = 0; k < w; ++k) woff += wsum[k];
    int excl = blockoff + woff + incl - v;
    if (gid < NN) rstart[gid] = excl;
    if (gid == 0) rstart[NN] = EE;
}

// atomic-free scatter using precomputed ranks
__global__ void scatter_kernel(const void* __restrict__ ei, const int* __restrict__ flag,
                               const int* __restrict__ rank, const int* __restrict__ rstart,
                               int* __restrict__ colS) {
    int i = (blockIdx.x * blockDim.x + threadIdx.x) * 2;
    if (i >= EE) return;
    int r0, r1, c0, c1;
    if (*flag) {
        longlong2 rv = *(const longlong2*)((const long long*)ei + i);
        longlong2 cv = *(const longlong2*)((const long long*)ei + EE + i);
        r0 = (int)rv.x; r1 = (int)rv.y;
        c0 = (int)cv.x; c1 = (int)cv.y;
    } else {
        int2 rv = *(const int2*)((const int*)ei + i);
        int2 cv = *(const int2*)((const int*)ei + EE + i);
        r0 = rv.x; r1 = rv.y;
        c0 = cv.x; c1 = cv.y;
    }
    int2 rk = *(const int2*)(rank + i);
    colS[rstart[r0] + rk.x] = c0;
    colS[rstart[r1] + rk.y] = c1;
}

// ---------------- pack weights into MFMA b-fragment order ----------------
__global__ void pack_w_kernel(const float* __restrict__ Wq, const float* __restrict__ Wk,
                              const float* __restrict__ Wv, const float* __restrict__ W1,
                              const float* __restrict__ W2, unsigned short* __restrict__ wf) {
    int i = blockIdx.x * blockDim.x + threadIdx.x;
    if (i >= 98304) return;
    float val;
    if (i < 49152) {                      // QKV: ntiles=24, ksteps=4, K=128
        int j = i & 7, lane = (i >> 3) & 63, kk = (i >> 9) & 3, nt = i >> 11;
        int k = kk * 32 + (lane >> 4) * 8 + j;
        int n = nt * 16 + (lane & 15);    // 0..383
        const float* W = (n < 128) ? Wq : ((n < 256) ? Wk : Wv);
        val = W[k * HH + (n & 127)];
    } else if (i < 81920) {               // W1: ntiles=8, ksteps=8, K=256
        int local = i - 49152;
        int j = local & 7, lane = (local >> 3) & 63, kk = (local >> 9) & 7, nt = local >> 12;
        int k = kk * 32 + (lane >> 4) * 8 + j;
        int n = nt * 16 + (lane & 15);
        val = W1[k * HH + n];
    } else {                              // W2: ntiles=8, ksteps=4, K=128
        int local = i - 81920;
        int j = local & 7, lane = (local >> 3) & 63, kk = (local >> 9) & 3, nt = local >> 11;
        int k = kk * 32 + (lane >> 4) * 8 + j;
        int n = nt * 16 + (lane & 15);
        val = W2[k * HH + n];
    }
    wf[i] = f2bf(val);
}

// ---------------- fused x-pack + QKV GEMM via MFMA ----------------
// Q/K stored as f16 (for v_dot2 in attn); V stored bf16
__global__ __launch_bounds__(256) void qkvx_kernel(
        const float* __restrict__ x, const unsigned short* __restrict__ wf,
        const float* __restrict__ bq, const float* __restrict__ bk, const float* __restrict__ bv,
        unsigned short* __restrict__ xa,
        unsigned short* __restrict__ Qb, unsigned short* __restrict__ Kb,
        unsigned short* __restrict__ Vb) {
    const int wave = threadIdx.x >> 6, lane = threadIdx.x & 63;
    const int row0 = blockIdx.x * 64 + wave * 16;
    const int arow = row0 + (lane & 15);
    const int kbase = (lane >> 4) * 8;

    s16x8 a[4];
    if (arow < NN) {
        const float* xp = x + (size_t)arow * HH + kbase;
        #pragma unroll
        for (int kk = 0; kk < 4; ++kk) {
            float4 f0 = *(const float4*)(xp + kk * 32);
            float4 f1 = *(const float4*)(xp + kk * 32 + 4);
            s16x8 av;
            av[0] = (short)f2bf(f0.x); av[1] = (short)f2bf(f0.y);
            av[2] = (short)f2bf(f0.z); av[3] = (short)f2bf(f0.w);
            av[4] = (short)f2bf(f1.x); av[5] = (short)f2bf(f1.y);
            av[6] = (short)f2bf(f1.z); av[7] = (short)f2bf(f1.w);
            a[kk] = av;
            *(s16x8*)(xa + (size_t)arow * 256 + kbase + kk * 32) = av;
        }
    } else {
        #pragma unroll
        for (int kk = 0; kk < 4; ++kk) a[kk] = (s16x8)0;
    }

    f32x4 acc[24];
    #pragma unroll
    for (int nt = 0; nt < 24; ++nt) acc[nt] = (f32x4){0.f, 0.f, 0.f, 0.f};

    const s16x8* wfv = (const s16x8*)wf;
    #pragma unroll
    for (int nt = 0; nt < 24; ++nt) {
        #pragma unroll
        for (int kk = 0; kk < 4; ++kk) {
            s16x8 b = wfv[(nt * 4 + kk) * 64 + lane];
            acc[nt] = mfma_bf16(a[kk], b, acc[nt]);
        }
    }

    const int colb = lane & 15;
    const int rbase = row0 + (lane >> 4) * 4;
    #pragma unroll
    for (int nt = 0; nt < 24; ++nt) {
        const int mtx = nt >> 3;                  // 0:Q 1:K 2:V
        const int nc = (nt & 7) * 16 + colb;      // 0..127
        const float* bias_p = (mtx == 0) ? bq : ((mtx == 1) ? bk : bv);
        unsigned short* O = (mtx == 0) ? Qb : ((mtx == 1) ? Kb : Vb);
        float bias = bias_p[nc];
        #pragma unroll
        for (int r = 0; r < 4; ++r) {
            float v = acc[nt][r] + bias;
            O[(size_t)(rbase + r) * 128 + nc] = (mtx == 2) ? f2bf(v) : f2h(v);
        }
    }
}

// ---------------- fused per-node attention: one node per wave ----------------
// score phase: lane = local_edge*4 + head (lane-local 32-dim f16 dot via v_dot2)
// PV phase: half = lane>>5 handles edges of that parity; lane owns dims 4*sl..4*sl+3
__global__ __launch_bounds__(256) void attn_kernel(
        const unsigned short* __restrict__ Qb, const unsigned short* __restrict__ Kb,
        const unsigned short* __restrict__ Vb, const int* __restrict__ rstart,
        const int* __restrict__ colS, unsigned short* __restrict__ xa) {
    const int wave = threadIdx.x >> 6;
    const int lane = threadIdx.x & 63;
    const int i = blockIdx.x * 4 + wave;
    if (i >= NN) return;
    const int h = lane & 3;       // head (score phase)
    const int le = lane >> 2;     // local edge 0..15 (score phase)
    const int half = lane >> 5;   // PV: edge parity
    const int sl = lane & 31;     // PV: dim group (4 dims)
    const int g2 = sl >> 3;       // PV: head of owned dims
    const int e0 = rstart[i], e1 = rstart[i + 1];
    const int deg = e1 - e0;

    // Q slice for this head: 32 f16 packed in 4 x uint4 (no unpack needed)
    uint4 q[4];
    {
        const uint4* qp = (const uint4*)(Qb + (size_t)i * 128 + h * 32);
        #pragma unroll
        for (int c = 0; c < 4; ++c) q[c] = qp[c];
    }

    float m = -INFINITY, l = 0.f;
    float acc0 = 0.f, acc1 = 0.f, acc2 = 0.f, acc3 = 0.f;

    for (int c0 = 0; c0 < deg; c0 += 16) {
        const int cnt = min(16, deg - c0);
        int col = 0;
        if (le < cnt) col = colS[e0 + c0 + le];
        const uint4* kp = (const uint4*)(Kb + (size_t)col * 128 + h * 32);
        uint4 k0 = kp[0], k1 = kp[1], k2 = kp[2], k3 = kp[3];
        // 4 independent fdot2 chains, summed at the end
        float d0 = 0.f, d1 = 0.f, d2 = 0.f, d3 = 0.f;
        d0 = fdot2u(k0.x, q[0].x, d0); d0 = fdot2u(k0.y, q[0].y, d0);
        d0 = fdot2u(k0.z, q[0].z, d0); d0 = fdot2u(k0.w, q[0].w, d0);
        d1 = fdot2u(k1.x, q[1].x, d1); d1 = fdot2u(k1.y, q[1].y, d1);
        d1 = fdot2u(k1.z, q[1].z, d1); d1 = fdot2u(k1.w, q[1].w, d1);
        d2 = fdot2u(k2.x, q[2].x, d2); d2 = fdot2u(k2.y, q[2].y, d2);
        d2 = fdot2u(k2.z, q[2].z, d2); d2 = fdot2u(k2.w, q[2].w, d2);
        d3 = fdot2u(k3.x, q[3].x, d3); d3 = fdot2u(k3.y, q[3].y, d3);
        d3 = fdot2u(k3.z, q[3].z, d3); d3 = fdot2u(k3.w, q[3].w, d3);
        float s = -INFINITY;
        if (le < cnt) s = ((d0 + d1) + (d2 + d3)) * 0.17677669529663689f;  // 1/sqrt(32)
        // per-head reduce over the 16 edge-lanes (lane stride 4)
        float sm = s;
        sm = fmaxf(sm, __shfl_xor(sm, 4));
        sm = fmaxf(sm, __shfl_xor(sm, 8));
        sm = fmaxf(sm, __shfl_xor(sm, 16));
        sm = fmaxf(sm, __shfl_xor(sm, 32));
        const float mn = fmaxf(m, sm);
        const float p = (le < cnt) ? __expf(s - mn) : 0.f;
        float ps = p;
        ps += __shfl_xor(ps, 4);
        ps += __shfl_xor(ps, 8);
        ps += __shfl_xor(ps, 16);
        ps += __shfl_xor(ps, 32);
        const float fac = __expf(m - mn);   // first chunk: exp(-inf)=0
        l = l * fac + ps;
        m = mn;
        // PV: each half handles 8 edges of its parity; 4 dims per lane (dwordx2)
        const float facbc = __shfl(fac, g2);
        acc0 *= facbc; acc1 *= facbc; acc2 *= facbc; acc3 *= facbc;
        #pragma unroll
        for (int e2 = 0; e2 < 8; ++e2) {
            const int e = 2 * e2 + half;
            const int   cbc = __shfl(col, 4 * e);
            const float pbc = __shfl(p, 4 * e + g2);
            const uint2 v2 = *(const uint2*)(Vb + (size_t)cbc * 128 + 4 * sl);
            acc0 += pbc * bflo(v2.x);
            acc1 += pbc * bfhi(v2.x);
            acc2 += pbc * bflo(v2.y);
            acc3 += pbc * bfhi(v2.y);
        }
    }

    // combine the two edge-parity halves
    acc0 += __shfl_xor(acc0, 32);
    acc1 += __shfl_xor(acc1, 32);
    acc2 += __shfl_xor(acc2, 32);
    acc3 += __shfl_xor(acc3, 32);
    const float lf = __shfl(l, g2);
    const float rinv = (lf > 0.f) ? 1.f / lf : 0.f;
    if (half == 0) {
        uint2 o;
        o.x = ((unsigned int)f2bf(acc1 * rinv) << 16) | (unsigned int)f2bf(acc0 * rinv);
        o.y = ((unsigned int)f2bf(acc3 * rinv) << 16) | (unsigned int)f2bf(acc2 * rinv);
        *(uint2*)(xa + (size_t)i * 256 + 128 + 4 * sl) = o;
    }
}

// ---------------- fused MLP: GEMM1 + ReLU + LN -> LDS -> GEMM2 + bias + residual ----------------
#define HROW 136   // padded LDS row (shorts): 272B stride -> 2-way max bank aliasing on b128 reads
__global__ __launch_bounds__(256) void mlp_fused_kernel(
        const unsigned short* __restrict__ xa, const unsigned short* __restrict__ w1f,
        const float* __restrict__ b1, const float* __restrict__ ln_g,
        const float* __restrict__ ln_b, const unsigned short* __restrict__ w2f,
        const float* __restrict__ b2, float* __restrict__ out) {
    __shared__ unsigned short hs[64 * HROW];
    const int wave = threadIdx.x >> 6, lane = threadIdx.x & 63;
    const int row0 = blockIdx.x * 64 + wave * 16;
    const int arow = row0 + (lane & 15);
    const int colb = lane & 15;

    // ---- GEMM1: [64x256] @ W1 -> h [64x128]
    s16x8 a[8];
    const unsigned short* ap = xa + (size_t)arow * 256 + (lane >> 4) * 8;
    #pragma unroll
    for (int kk = 0; kk < 8; ++kk) a[kk] = *(const s16x8*)(ap + kk * 32);

    f32x4 acc[8];
    #pragma unroll
    for (int nt = 0; nt < 8; ++nt) acc[nt] = (f32x4){0.f, 0.f, 0.f, 0.f};

    const s16x8* w1v = (const s16x8*)w1f;
    #pragma unroll
    for (int nt = 0; nt < 8; ++nt) {
        #pragma unroll
        for (int kk = 0; kk < 8; ++kk) {
            s16x8 b = w1v[(nt * 8 + kk) * 64 + lane];
            acc[nt] = mfma_bf16(a[kk], b, acc[nt]);
        }
    }

    // bias + relu
    #pragma unroll
    for (int nt = 0; nt < 8; ++nt) {
        float bias = b1[nt * 16 + colb];
        #pragma unroll
        for (int r = 0; r < 4; ++r) {
            float v = acc[nt][r] + bias;
            acc[nt][r] = v > 0.f ? v : 0.f;
        }
    }
    // LayerNorm across the 128 cols (8 ntiles x 16 lanes)
    float mu[4], rs[4];
    #pragma unroll
    for (int r = 0; r < 4; ++r) {
        float s = 0.f, q = 0.f;
        #pragma unroll
        for (int nt = 0; nt < 8; ++nt) { float v = acc[nt][r]; s += v; q += v * v; }
        #pragma unroll
        for (int msk = 1; msk < 16; msk <<= 1) {
            s += __shfl_xor(s, msk, 16);
            q += __shfl_xor(q, msk, 16);
        }
        float m_ = s * (1.f / 128.f);
        float var = q * (1.f / 128.f) - m_ * m_;
        mu[r] = m_;
        rs[r] = rsqrtf(var + LN_EPS);
    }
    // scale/shift and stage h tile to LDS (bf16)
    const int lrbase = wave * 16 + (lane >> 4) * 4;   // local row base
    #pragma unroll
    for (int nt = 0; nt < 8; ++nt) {
        int col = nt * 16 + colb;
        float g = ln_g[col], bb = ln_b[col];
        #pragma unroll
        for (int r = 0; r < 4; ++r) {
            float hv = (acc[nt][r] - mu[r]) * rs[r] * g + bb;
            hs[(lrbase + r) * HROW + col] = f2bf(hv);
        }
    }
    __syncthreads();

    // ---- GEMM2: h [64x128] @ W2 -> out + bias + residual
    const int la = wave * 16 + (lane & 15);
    s16x8 a2[4];
    const unsigned short* hp = hs + la * HROW + (lane >> 4) * 8;
    #pragma unroll
    for (int kk = 0; kk < 4; ++kk) a2[kk] = *(const s16x8*)(hp + kk * 32);

    f32x4 acc2[8];
    #pragma unroll
    for (int nt = 0; nt < 8; ++nt) acc2[nt] = (f32x4){0.f, 0.f, 0.f, 0.f};

    const s16x8* w2v = (const s16x8*)w2f;
    #pragma unroll
    for (int nt = 0; nt < 8; ++nt) {
        #pragma unroll
        for (int kk = 0; kk < 4; ++kk) {
            s16x8 b = w2v[(nt * 4 + kk) * 64 + lane];
            acc2[nt] = mfma_bf16(a2[kk], b, acc2[nt]);
        }
    }

    const int rbase = row0 + (lane >> 4) * 4;
    #pragma unroll
    for (int nt = 0; nt < 8; ++nt) {
        int col = nt * 16 + colb;
        float bias = b2[col];
        #pragma unroll
        for (int r = 0; r < 4; ++r) {
            int row = rbase + r;
            if (row < NN)
                out[(size_t)row * 128 + col] =
                    acc2[nt][r] + bias + bf2f(xa[(size_t)row * 256 + col]);
        }
    }
}

extern "C" void kernel_launch(void* const* d_in, const int* in_sizes, int n_in,
                              void* d_out, int out_size, void* d_ws, size_t ws_size,
                              hipStream_t stream) {
    const float* x    = (const float*)d_in[0];
    const void*  ei   = d_in[1];
    const float* Wq   = (const float*)d_in[2];
    const float* bq   = (const float*)d_in[3];
    const float* Wk   = (const float*)d_in[4];
    const float* bk   = (const float*)d_in[5];
    const float* Wv   = (const float*)d_in[6];
    const float* bv   = (const float*)d_in[7];
    const float* W1   = (const float*)d_in[8];
    const float* b1   = (const float*)d_in[9];
    const float* ln_g = (const float*)d_in[10];
    const float* ln_b = (const float*)d_in[11];
    const float* W2   = (const float*)d_in[12];
    const float* b2   = (const float*)d_in[13];
    float* out = (float*)d_out;

    char* ws = (char*)d_ws;
    size_t off = 0;
    auto alloc = [&](size_t bytes) {
        size_t o = off;
        off = (off + bytes + 255) & ~(size_t)255;
        return o;
    };
    size_t flag_o = alloc(sizeof(int));
    size_t deg_o  = alloc((size_t)NN * sizeof(int));
    size_t rank_o = alloc((size_t)EE * sizeof(int));
    size_t rs_o   = alloc((size_t)(NN + 1) * sizeof(int));
    size_t bsum_o = alloc((size_t)SCAN_NB * sizeof(int));
    size_t colS_o = alloc((size_t)EE * sizeof(int));
    size_t xa_o   = alloc((size_t)ROWS_PAD * 256 * sizeof(unsigned short));
    size_t wf_o   = alloc((size_t)98304 * sizeof(unsigned short));
    size_t Qb_o   = alloc((size_t)ROWS_PAD * 128 * sizeof(unsigned short));
    size_t Kb_o   = alloc((size_t)ROWS_PAD * 128 * sizeof(unsigned short));
    size_t Vb_o   = alloc((size_t)ROWS_PAD * 128 * sizeof(unsigned short));

    int* flag   = (int*)(ws + flag_o);
    int* deg    = (int*)(ws + deg_o);
    int* rank   = (int*)(ws + rank_o);
    int* rstart = (int*)(ws + rs_o);
    int* bsum   = (int*)(ws + bsum_o);
    int* colS   = (int*)(ws + colS_o);
    unsigned short* xa = (unsigned short*)(ws + xa_o);
    unsigned short* wf = (unsigned short*)(ws + wf_o);
    unsigned short* Qb = (unsigned short*)(ws + Qb_o);
    unsigned short* Kb = (unsigned short*)(ws + Kb_o);
    unsigned short* Vb = (unsigned short*)(ws + Vb_o);

    hipMemsetAsync(ws + deg_o, 0, (size_t)NN * sizeof(int), stream);

    detect_idx_kernel<<<1, 64, 0, stream>>>((const unsigned int*)ei, flag);
    hist_kernel<<<(EE / 2 + 255) / 256, 256, 0, stream>>>(ei, flag, deg, rank);
    scan_a_kernel<<<SCAN_NB, 512, 0, stream>>>(deg, bsum);
    scan_c_kernel<<<SCAN_NB, 512, 0, stream>>>(deg, bsum, rstart);
    scatter_kernel<<<(EE / 2 + 255) / 256, 256, 0, stream>>>(ei, flag, rank, rstart, colS);

    pack_w_kernel<<<98304 / 256, 256, 0, stream>>>(Wq, Wk, Wv, W1, W2, wf);

    qkvx_kernel<<<ROWS_PAD / 64, 256, 0, stream>>>(x, wf, bq, bk, bv, xa, Qb, Kb, Vb);

    attn_kernel<<<(NN + 3) / 4, 256, 0, stream>>>(Qb, Kb, Vb, rstart, colS, xa);

    mlp_fused_kernel<<<ROWS_PAD / 64, 256, 0, stream>>>(
        xa, wf + 49152, b1, ln_g, ln_b, wf + 81920, b2, out);
}